// Round 10
// baseline (161.666 us; speedup 1.0000x reference)
//
#include <hip/hip_runtime.h>
#include <hip/hip_bf16.h>
#include <stdint.h>

// Problem constants (fixed by reference)
#define T_TASKS 8
#define DM      1024
#define HID     1024
#define NC      100
#define NCP     128
#define BATCH   8192
#define MPAD    9216      // 8192 + 8*128 worst-case 128-aligned padding

typedef __bf16 bf16x8 __attribute__((ext_vector_type(8)));
typedef float  f32x4  __attribute__((ext_vector_type(4)));
typedef unsigned int u32;
#define GAS __attribute__((address_space(1)))
#define LAS __attribute__((address_space(3)))

__device__ __forceinline__ unsigned short f2bf(float f) {
  __hip_bfloat16 h = __float2bfloat16(f);
  return __builtin_bit_cast(unsigned short, h);
}

__device__ __forceinline__ float bf2f(unsigned short u) {
  const u32 v = ((u32)u) << 16;
  return __builtin_bit_cast(float, v);
}

// ---------------------------------------------------------------------------
// count: per-block LDS histogram -> gcount[b][t] (no atomics, no init pass).
// Also clears its stripe of perm to -1. grid 32 x 256.
// ---------------------------------------------------------------------------
__global__ void count_k(const int* __restrict__ task_id,
                        int* __restrict__ gcount, int* __restrict__ perm) {
  __shared__ int h[T_TASKS];
  const int tid = threadIdx.x;
  const int bx  = blockIdx.x;
  if (tid < T_TASKS) h[tid] = 0;
  __syncthreads();
  atomicAdd(&h[task_id[bx * 256 + tid]], 1);
  const int base = bx * (MPAD / 32);           // 288 per block
  for (int i = tid; i < MPAD / 32; i += 256) perm[base + i] = -1;
  __syncthreads();
  if (tid < T_TASKS) gcount[bx * T_TASKS + tid] = h[tid];
}

// ---------------------------------------------------------------------------
// scatter: each block computes totals + its own prefix from gcount (1024 B),
// then scatters its 256 rows. grid 32 x 256.
// ---------------------------------------------------------------------------
__global__ void scatter_k(const int* __restrict__ task_id,
                          const int* __restrict__ gcount,
                          int* __restrict__ perm, int* __restrict__ starts) {
  __shared__ int h[T_TASKS];
  __shared__ int tot[T_TASKS], prev[T_TASKS];
  __shared__ int sst[T_TASKS + 1];
  const int tid = threadIdx.x;
  const int bx  = blockIdx.x;
  if (tid < T_TASKS) {
    h[tid] = 0;
    int s = 0, p = 0;
    for (int b = 0; b < 32; ++b) {
      const int c = gcount[b * T_TASKS + tid];
      s += c;
      if (b < bx) p += c;
    }
    tot[tid] = s; prev[tid] = p;
  }
  __syncthreads();
  if (tid == 0) {
    int off = 0;
    for (int t = 0; t < T_TASKS; ++t) { sst[t] = off; off += (tot[t] + 127) & ~127; }
    sst[T_TASKS] = off;
  }
  const int r = bx * 256 + tid;
  const int t = task_id[r];
  const int slot = atomicAdd(&h[t], 1);
  __syncthreads();
  perm[sst[t] + prev[t] + slot] = r;
  if (bx == 0 && tid <= T_TASKS) starts[tid] = sst[tid];
}

// ---------------------------------------------------------------------------
// preproc_fused: one launch, three block roles (UNCHANGED from round 9).
// ---------------------------------------------------------------------------
#define GX_BLKS MPAD
#define W1_BLKS (T_TASKS * 16 * 16)
#define W2_BLKS (16 * T_TASKS)
__global__ void preproc_fused(const float* __restrict__ x,
                              const int* __restrict__ perm,
                              unsigned short* __restrict__ XP,
                              const float* __restrict__ W1,
                              unsigned short* __restrict__ W1T,
                              const float* __restrict__ W2,
                              unsigned short* __restrict__ W2F) {
  __shared__ unsigned short tile[128 * 72];    // 18,432 B (max of roles)
  const int bid = blockIdx.x;
  const int tid = threadIdx.x;

  if (bid < GX_BLKS) {
    // ---- gather + convert x ----
    const int r = perm[bid];
    const int c = tid * 4;
    ushort4 v;
    if (r >= 0) {
      const float4 f = *(const float4*)(x + (size_t)r * DM + c);
      v.x = f2bf(f.x); v.y = f2bf(f.y); v.z = f2bf(f.z); v.w = f2bf(f.w);
    } else {
      v.x = 0; v.y = 0; v.z = 0; v.w = 0;
    }
    *(ushort4*)(XP + (size_t)bid * DM + c) = v;
    return;
  }

  if (bid < GX_BLKS + W1_BLKS) {
    // ---- W1 transpose, vectorized global sides ----
    const int b  = bid - GX_BLKS;
    const int t  = b >> 8;
    const int rem = b & 255;
    const int d0 = (rem >> 4) * 64;
    const int h0 = (rem & 15) * 64;
    const float* src = W1 + (size_t)t * DM * HID;
    unsigned short* dst = W1T + (size_t)t * HID * DM;
#pragma unroll
    for (int i = 0; i < 4; ++i) {
      const int idx = tid + 256 * i;           // 1024 float4 = 64d x 16 chunks
      const int d  = idx >> 4;
      const int hc = (idx & 15) * 4;
      const float4 f = *(const float4*)(src + (size_t)(d0 + d) * HID + h0 + hc);
      tile[(hc + 0) * 65 + d] = f2bf(f.x);
      tile[(hc + 1) * 65 + d] = f2bf(f.y);
      tile[(hc + 2) * 65 + d] = f2bf(f.z);
      tile[(hc + 3) * 65 + d] = f2bf(f.w);
    }
    __syncthreads();
#pragma unroll
    for (int i = 0; i < 2; ++i) {
      const int idx = tid + 256 * i;           // 512 ushort8 = 64h x 8 chunks
      const int lh  = idx >> 3;
      const int ldc = idx & 7;
      union { uint4 v; unsigned short s[8]; } o;
#pragma unroll
      for (int q = 0; q < 8; ++q) o.s[q] = tile[lh * 65 + ldc * 8 + q];
      *(uint4*)(dst + (size_t)(h0 + lh) * DM + d0 + ldc * 8) = o.v;
    }
    return;
  }

  // ---- W2 -> frag-packed W2F ----
  {
    const int b  = bid - (GX_BLKS + W1_BLKS);
    const int t  = b >> 4;
    const int h0 = (b & 15) * 64;
    const float* src = W2 + (size_t)t * HID * NC;
#pragma unroll
    for (int i = 0; i < 36; ++i) tile[tid + 256 * i] = 0;
    __syncthreads();
#pragma unroll
    for (int i = 0; i < 32; ++i) {
      const int idx = tid + 256 * i;
      const int row = idx >> 7, col = idx & 127;
      if (col < NC)
        tile[col * 72 + row] = f2bf(src[(size_t)(h0 + row) * NC + col]);
    }
    __syncthreads();
    const int w = tid >> 6, lane = tid & 63;
    const int lr = lane & 15, quad = lane >> 4;
#pragma unroll
    for (int e = 0; e < 4; ++e) {
      const int fi = w * 4 + e;
      const int ci = fi >> 1, kcl = fi & 1;
      const uint4 v = *(const uint4*)&tile[(ci * 16 + lr) * 72 + kcl * 32 + quad * 8];
      unsigned short* dstp =
          W2F + (((size_t)t * 8 + ci) * 32 + (h0 >> 5) + kcl) * 512 + lane * 8;
      *(uint4*)dstp = v;
    }
  }
}

// ---------------------------------------------------------------------------
// Fused MLP GEMM, BK=128 (vs proven BK=64): halves the number of barrier
// vmcnt-drains (8 K-iters instead of 16, 64 MFMA/wave/barrier) at an LDS
// cost of 64 KB -> 2 blocks/CU (was effective 2.25). Staging: 16 chunks/row,
// XOR swizzle on low 3 bits of chunk col (crow&7 is i-invariant: 16*i = 0
// mod 8). All epilogue / mm2 / store logic byte-identical to round 8/9.
// ---------------------------------------------------------------------------
__global__ __launch_bounds__(256, 2) void gemm_fused5(
    const unsigned short* __restrict__ XP,     // [MPAD][1024] bf16 permuted
    const unsigned short* __restrict__ W1T,    // [T][HID][1024] bf16
    const unsigned short* __restrict__ W2F,    // [T][8][32][512] frag-packed
    const float* __restrict__ b1,              // [T][HID]
    const int* __restrict__ starts,            // [9]
    unsigned short* __restrict__ Lp)           // [8][MPAD][128] bf16 partials
{
  __shared__ __align__(16) unsigned short lds[32768];  // 65,536 B
  unsigned short* As = lds;                    // [128 rows][16 chunks][8 shorts]
  unsigned short* Bs = lds + 16384;            // same
  unsigned short* hS = lds;                    // reuse: [128][136]

  const int tid = threadIdx.x;
  const int p0  = blockIdx.x * 128;
  const int n0  = blockIdx.y * 128;

  if (p0 >= starts[T_TASKS]) return;           // all-pad tail tile: skip

  int task = 0;
#pragma unroll
  for (int t = 1; t < T_TASKS; ++t)
    if (p0 >= starts[t]) task = t;

  const int wave = tid >> 6;
  const int lane = tid & 63;
  const int wm   = (wave >> 1) * 64;
  const int wn   = (wave & 1) * 64;
  const int lr   = lane & 15;
  const int quad = lane >> 4;

  // --- staging: 2048 16B-chunks per matrix per iter; thread t covers chunk
  // t + 256*i (i<8). crow = chunk>>4 = (tid>>4) + 16*i; ccol = tid&15.
  // Source k-chunk = ccol ^ (crow&7); crow&7 = (tid>>4)&7 for all i.
  const int crow0 = tid >> 4;                  // 0..15
  const int kc    = (tid & 15) ^ (crow0 & 7);
  const unsigned short* pA[8];
  const unsigned short* pB[8];
  const unsigned short* Bg = W1T + ((size_t)task * HID + n0) * 1024;
#pragma unroll
  for (int i = 0; i < 8; ++i) {
    const int row = crow0 + 16 * i;
    pA[i] = XP + (size_t)(p0 + row) * 1024 + kc * 8;
    pB[i] = Bg + (size_t)row * 1024 + kc * 8;
  }

  f32x4 acc[4][4];
#pragma unroll
  for (int i = 0; i < 4; ++i)
#pragma unroll
    for (int j = 0; j < 4; ++j) acc[i][j] = (f32x4){0.f, 0.f, 0.f, 0.f};

  // LDS read chunk cols for the 4 k-steps (source chunk kk*4+quad at
  // swizzled position (kk*4+quad) ^ (row&7); row&7 == lr&7).
  int sw[4];
#pragma unroll
  for (int kk = 0; kk < 4; ++kk) sw[kk] = (kk * 4 + quad) ^ (lr & 7);

  for (int k0 = 0; k0 < 1024; k0 += 128) {
#pragma unroll
    for (int i = 0; i < 8; ++i) {
      __builtin_amdgcn_global_load_lds((const GAS u32*)(pA[i] + k0),
                                       (LAS u32*)&As[(tid + 256 * i) * 8], 16, 0, 0);
      __builtin_amdgcn_global_load_lds((const GAS u32*)(pB[i] + k0),
                                       (LAS u32*)&Bs[(tid + 256 * i) * 8], 16, 0, 0);
    }
    __syncthreads();
#pragma unroll
    for (int kk = 0; kk < 4; ++kk) {
      bf16x8 a[4], b[4];
#pragma unroll
      for (int i = 0; i < 4; ++i)
        a[i] = *(const bf16x8*)&As[((wm + i * 16 + lr) * 16 + sw[kk]) * 8];
#pragma unroll
      for (int j = 0; j < 4; ++j)
        b[j] = *(const bf16x8*)&Bs[((wn + j * 16 + lr) * 16 + sw[kk]) * 8];
#pragma unroll
      for (int i = 0; i < 4; ++i)
#pragma unroll
        for (int j = 0; j < 4; ++j)
          acc[i][j] = __builtin_amdgcn_mfma_f32_16x16x32_bf16(a[i], b[j], acc[i][j], 0, 0, 0);
    }
    __syncthreads();
  }

  // --- h = relu(acc + b1) -> bf16 -> hS (C-layout in, A-layout rows) ---
  float b1v[4];
#pragma unroll
  for (int ni = 0; ni < 4; ++ni)
    b1v[ni] = b1[task * HID + n0 + wn + ni * 16 + lr];
#pragma unroll
  for (int mi = 0; mi < 4; ++mi)
#pragma unroll
    for (int r = 0; r < 4; ++r) {
      const int row = wm + mi * 16 + quad * 4 + r;
#pragma unroll
      for (int ni = 0; ni < 4; ++ni) {
        float v = acc[mi][ni][r] + b1v[ni];
        v = v > 0.f ? v : 0.f;
        hS[row * 136 + wn + ni * 16 + lr] = f2bf(v);
      }
    }
  __syncthreads();

  // --- mm2: h[128][128-slice] x W2 k-slice -> 128x128 partial logits ---
  const int cbase = (wave & 1) * 4;
  const unsigned short* pW2 =
      W2F + (((size_t)task * 8 + cbase) * 32 + blockIdx.y * 4) * 512 + lane * 8;

  f32x4 acc2[4][4];
#pragma unroll
  for (int mi = 0; mi < 4; ++mi)
#pragma unroll
    for (int ci = 0; ci < 4; ++ci) acc2[mi][ci] = (f32x4){0.f, 0.f, 0.f, 0.f};

#pragma unroll
  for (int e = 0; e < 4; ++e) {
    bf16x8 w2p[4], a2[4];
#pragma unroll
    for (int ci = 0; ci < 4; ++ci)
      w2p[ci] = *(const bf16x8*)(pW2 + ((size_t)ci * 32 + e) * 512);
#pragma unroll
    for (int mi = 0; mi < 4; ++mi)
      a2[mi] = *(const bf16x8*)&hS[(wm + mi * 16 + lr) * 136 + e * 32 + quad * 8];
#pragma unroll
    for (int mi = 0; mi < 4; ++mi)
#pragma unroll
      for (int ci = 0; ci < 4; ++ci)
        acc2[mi][ci] = __builtin_amdgcn_mfma_f32_16x16x32_bf16(
            a2[mi], w2p[ci], acc2[mi][ci], 0, 0, 0);
  }

  // --- store bf16 partials, plain coalesced (no atomics) ---
  unsigned short* lp = Lp + ((size_t)blockIdx.y * MPAD + p0) * NCP;
#pragma unroll
  for (int mi = 0; mi < 4; ++mi)
#pragma unroll
    for (int r = 0; r < 4; ++r) {
      const int row = wm + mi * 16 + quad * 4 + r;
#pragma unroll
      for (int ci = 0; ci < 4; ++ci)
        lp[row * NCP + wn + ci * 16 + lr] = f2bf(acc2[mi][ci][r]);
    }
}

// ---------------------------------------------------------------------------
// reduce: sum 8 bf16 partial slices, +b2, scatter to out via perm. UNCHANGED.
// ---------------------------------------------------------------------------
__global__ void reduce_k(const unsigned short* __restrict__ Lp,
                         const int* __restrict__ perm,
                         const int* __restrict__ task_id,
                         const float* __restrict__ b2,
                         float* __restrict__ Out) {
  const int gid = blockIdx.x * 256 + threadIdx.x;
  const int row = gid >> 5;
  const int c4  = (gid & 31) * 4;
  if (c4 >= NC) return;
  const int og = perm[row];
  if (og < 0) return;
  float s0 = 0.f, s1 = 0.f, s2 = 0.f, s3 = 0.f;
#pragma unroll
  for (int sp = 0; sp < 8; ++sp) {
    const ushort4 v = *(const ushort4*)(Lp + ((size_t)sp * MPAD + row) * NCP + c4);
    s0 += bf2f(v.x); s1 += bf2f(v.y); s2 += bf2f(v.z); s3 += bf2f(v.w);
  }
  const int task = task_id[og];
  const float4 bb = *(const float4*)(b2 + (size_t)task * NC + c4);
  float4 o;
  o.x = s0 + bb.x; o.y = s1 + bb.y; o.z = s2 + bb.z; o.w = s3 + bb.w;
  *(float4*)(Out + (size_t)og * NC + c4) = o;
}

// ---------------------------------------------------------------------------
// Workspace layout (bytes) — total 56,688,640:
//   perm   int[9216]            @ 0           (36864)
//   gcount int[32*8]            @ 36864       (1024)
//   starts int[9]               @ 37888
//   XP     bf16[9216*1024]      @ 65536       (18874368)
//   W1T    bf16[8*1024*1024]    @ 18939904    (16777216)
//   W2F    bf16[8*8*32*512]     @ 35717120    (2097152)
//   Lp     bf16[8*9216*128]     @ 37814272    (18874368)  end 56688640
// ---------------------------------------------------------------------------
extern "C" void kernel_launch(void* const* d_in, const int* in_sizes, int n_in,
                              void* d_out, int out_size, void* d_ws, size_t ws_size,
                              hipStream_t stream) {
  const float* x       = (const float*)d_in[0];
  const int*   task_id = (const int*)d_in[1];
  const float* W1      = (const float*)d_in[2];
  const float* b1      = (const float*)d_in[3];
  const float* W2      = (const float*)d_in[4];
  const float* b2      = (const float*)d_in[5];
  float* out = (float*)d_out;

  char* ws = (char*)d_ws;
  int* perm   = (int*)(ws + 0);
  int* gcount = (int*)(ws + 36864);
  int* starts = (int*)(ws + 37888);
  unsigned short* XP  = (unsigned short*)(ws + 65536);
  unsigned short* W1T = (unsigned short*)(ws + 18939904);
  unsigned short* W2F = (unsigned short*)(ws + 35717120);
  unsigned short* Lp  = (unsigned short*)(ws + 37814272);

  count_k<<<32, 256, 0, stream>>>(task_id, gcount, perm);
  scatter_k<<<32, 256, 0, stream>>>(task_id, gcount, perm, starts);
  preproc_fused<<<GX_BLKS + W1_BLKS + W2_BLKS, 256, 0, stream>>>(
      x, perm, XP, W1, W1T, W2, W2F);
  gemm_fused5<<<dim3(MPAD / 128, HID / 128), 256, 0, stream>>>(
      XP, W1T, W2F, b1, starts, Lp);
  reduce_k<<<MPAD * 32 / 256, 256, 0, stream>>>(Lp, perm, task_id, b2, out);
}